// Round 3
// baseline (390.250 us; speedup 1.0000x reference)
//
#include <hip/hip_runtime.h>
#include <math.h>

// Problem constants (from setup_inputs)
#define BB   8
#define CXH  16
#define CXL  8
#define HH   256
#define HL   512

// Tiling
#define TS   32              // 512-res tile edge
#define HALO 2
#define GT   (TS + 2*HALO)   // 36 : LN'd tile + halo
#define GP   38              // padded (even) row pitch for s_gln -> b64-aligned
#define QT   (TS/2)          // 16 : 256-res tile edge
#define DT   (QT + 2)        // 18 : 256-res tile + halo1

typedef _Float16 f16x4 __attribute__((ext_vector_type(4)));

__device__ __forceinline__ float gelu_exact(float x) {
    return 0.5f * x * (1.0f + erff(x * 0.70710678118654752f));
}

// ---------------------------------------------------------------------------
// Kernel A: 1x1 conv (16->8) of xh, written channel-interleaved [B][H][W][8]
// into workspace (16.8 MB -> L2/L3 resident for the main kernel).
// ---------------------------------------------------------------------------
__global__ __launch_bounds__(256)
void pre_project_kernel(const float* __restrict__ xh,
                        const float* __restrict__ pre_w,
                        const float* __restrict__ pre_b,
                        float* __restrict__ xhp)
{
    const int idx = blockIdx.x * 256 + threadIdx.x;   // over B*256*256
    const int b  = idx >> 16;
    const int px = idx & 0xFFFF;
    const float* xp = xh + (size_t)(b * CXH) * (HH * HH) + px;
    float xv[16];
    #pragma unroll
    for (int c = 0; c < 16; ++c) xv[c] = xp[c * HH * HH];
    float4 o0, o1;
    float oc[8];
    #pragma unroll
    for (int o = 0; o < 8; ++o) {
        float a = pre_b[o];
        #pragma unroll
        for (int c = 0; c < 16; ++c) a += pre_w[o * 16 + c] * xv[c];
        oc[o] = a;
    }
    o0.x = oc[0]; o0.y = oc[1]; o0.z = oc[2]; o0.w = oc[3];
    o1.x = oc[4]; o1.y = oc[5]; o1.z = oc[6]; o1.w = oc[7];
    float4* dst = (float4*)(xhp + (size_t)idx * 8);
    dst[0] = o0; dst[1] = o1;
}

// ---------------------------------------------------------------------------
// Main fused kernel
// ---------------------------------------------------------------------------
__global__ __launch_bounds__(256, 4)
void uem_fused_kernel(const float* __restrict__ xhp,   // [B][256][256][8]
                      const float* __restrict__ xl,
                      const float* __restrict__ mask,
                      const float* __restrict__ g_ln_w,
                      const float* __restrict__ g_ln_b,
                      const float* __restrict__ g_base_w,
                      const float* __restrict__ g_base_b,
                      const float* __restrict__ g_base_s,
                      const float* __restrict__ g_wt_w,
                      const float* __restrict__ g_wt_s,
                      const float* __restrict__ g_pw_w,
                      const float* __restrict__ tail_ln_w,
                      const float* __restrict__ tail_ln_b,
                      const float* __restrict__ tail_w,
                      const float* __restrict__ tail_b,
                      const float* __restrict__ res_w,
                      const float* __restrict__ res_b,
                      float* __restrict__ out)
{
    // LDS: 27360 + 12992 = 40352 B  ->  4 blocks/CU (16 waves/CU)
    __shared__ __align__(16) float    s_gln[5][GT][GP];        // LN'd branch input (fp32 planar)
    __shared__ __align__(16) _Float16 s_unh[DT * DT * 20 + 16]; // DWT subbands, fp16 interleaved

    const int b   = blockIdx.z;
    const int ty0 = blockIdx.y * TS;
    const int tx0 = blockIdx.x * TS;
    const int tx  = threadIdx.x, ty = threadIdx.y;
    const int tid = ty * 16 + tx;

    const float SC = (float)(255.0 / 511.0);   // align_corners scale, f32 as in JAX
    const float* xq = xhp + (size_t)b * (HH * HH * 8);

    // Per-quad-pixel accumulators for tail LN + tail 1x1 pre-products
    float S1[4] = {0.f, 0.f, 0.f, 0.f};
    float S2[4] = {0.f, 0.f, 0.f, 0.f};
    float T[4][8];
    #pragma unroll
    for (int p = 0; p < 4; ++p)
        #pragma unroll
        for (int o = 0; o < 8; ++o) T[p][o] = 0.f;

    for (int br = 0; br < 4; ++br) {
        const float lnw0 = g_ln_w[br * 5 + 0], lnw1 = g_ln_w[br * 5 + 1],
                    lnw2 = g_ln_w[br * 5 + 2], lnw3 = g_ln_w[br * 5 + 3],
                    lnw4 = g_ln_w[br * 5 + 4];
        const float lnb0 = g_ln_b[br * 5 + 0], lnb1 = g_ln_b[br * 5 + 1],
                    lnb2 = g_ln_b[br * 5 + 2], lnb3 = g_ln_b[br * 5 + 3],
                    lnb4 = g_ln_b[br * 5 + 4];

        // ---------- Phase 1: build LN'd gi (tile + halo2) in LDS ----------
        for (int idx = tid; idx < GT * GT; idx += 256) {
            const int ly = idx / GT, lx = idx % GT;
            const int gy = ty0 - HALO + ly, gx = tx0 - HALO + lx;
            float vv[5] = {0.f, 0.f, 0.f, 0.f, 0.f};
            if (gy >= 0 && gy < HL && gx >= 0 && gx < HL) {
                // bilinear (align_corners=True) sample of xh_p, 2 channels
                const float cy = (float)gy * SC;
                const int iy0 = min((int)cy, HH - 2);
                const float fy = cy - (float)iy0;
                const float cx = (float)gx * SC;
                const int ix0 = min((int)cx, HH - 2);
                const float fx = cx - (float)ix0;
                const float* q = xq + (iy0 * HH + ix0) * 8 + 2 * br;
                const float2 q00 = *(const float2*)(q);
                const float2 q01 = *(const float2*)(q + 8);
                const float2 q10 = *(const float2*)(q + HH * 8);
                const float2 q11 = *(const float2*)(q + HH * 8 + 8);
                {
                    const float top = q00.x + fx * (q01.x - q00.x);
                    const float bot = q10.x + fx * (q11.x - q10.x);
                    vv[0] = top + fy * (bot - top);
                }
                {
                    const float top = q00.y + fx * (q01.y - q00.y);
                    const float bot = q10.y + fx * (q11.y - q10.y);
                    vv[1] = top + fy * (bot - top);
                }
                const int xbase = ((b * CXL) * HL + gy) * HL + gx;
                vv[2] = xl[xbase + (2 * br) * HL * HL];
                vv[3] = xl[xbase + (2 * br + 1) * HL * HL];
                vv[4] = mask[(b * HL + gy) * HL + gx];
                const float u = (vv[0] + vv[1] + vv[2] + vv[3] + vv[4]) * 0.2f;
                float var = 0.f;
                #pragma unroll
                for (int c = 0; c < 5; ++c) { const float d = vv[c] - u; var += d * d; }
                var *= 0.2f;
                const float rstd = rsqrtf(var + 1e-6f);
                vv[0] = lnw0 * ((vv[0] - u) * rstd) + lnb0;
                vv[1] = lnw1 * ((vv[1] - u) * rstd) + lnb1;
                vv[2] = lnw2 * ((vv[2] - u) * rstd) + lnb2;
                vv[3] = lnw3 * ((vv[3] - u) * rstd) + lnb3;
                vv[4] = lnw4 * ((vv[4] - u) * rstd) + lnb4;
            }
            #pragma unroll
            for (int c = 0; c < 5; ++c) s_gln[c][ly][lx] = vv[c];
        }
        __syncthreads();

        // ---------- Phase 2: Haar DWT -> fp16 channel-interleaved subbands ----------
        for (int idx = tid; idx < DT * DT; idx += 256) {
            const int l = idx / DT, m = idx % DT;
            _Float16* dst = &s_unh[(l * DT + m) * 20];
            #pragma unroll
            for (int c = 0; c < 5; ++c) {
                const float2 t0 = *(const float2*)&s_gln[c][2 * l][2 * m];
                const float2 t1 = *(const float2*)&s_gln[c][2 * l + 1][2 * m];
                const float a  = t0.x, b2 = t0.y, c2 = t1.x, d2 = t1.y;
                f16x4 sb;
                sb.x = (_Float16)(0.5f * (a + b2 + c2 + d2));   // LL
                sb.y = (_Float16)(0.5f * (a + b2 - c2 - d2));   // LH
                sb.z = (_Float16)(0.5f * (a - b2 + c2 - d2));   // HL
                sb.w = (_Float16)(0.5f * (a - b2 - c2 + d2));   // HH
                *(f16x4*)(dst + c * 4) = sb;
            }
        }
        __syncthreads();

        // ---------- Phase 3: depthwise 3x3 on 20 subbands via fp16 b64 reads ----------
        float tag[20];
        #pragma unroll
        for (int j = 0; j < 20; ++j) tag[j] = 0.f;
        const float* wb = g_wt_w + br * 180;
        #pragma unroll
        for (int dy = 0; dy < 3; ++dy) {
            #pragma unroll
            for (int dx = 0; dx < 3; ++dx) {
                const _Float16* p = &s_unh[((ty + dy) * DT + (tx + dx)) * 20];
                const f16x4 v0 = *(const f16x4*)(p);
                const f16x4 v1 = *(const f16x4*)(p + 4);
                const f16x4 v2 = *(const f16x4*)(p + 8);
                const f16x4 v3 = *(const f16x4*)(p + 12);
                const f16x4 v4 = *(const f16x4*)(p + 16);
                const int wo = dy * 3 + dx;
                tag[0]  += wb[0  * 9 + wo] * (float)v0.x;  tag[1]  += wb[1  * 9 + wo] * (float)v0.y;
                tag[2]  += wb[2  * 9 + wo] * (float)v0.z;  tag[3]  += wb[3  * 9 + wo] * (float)v0.w;
                tag[4]  += wb[4  * 9 + wo] * (float)v1.x;  tag[5]  += wb[5  * 9 + wo] * (float)v1.y;
                tag[6]  += wb[6  * 9 + wo] * (float)v1.z;  tag[7]  += wb[7  * 9 + wo] * (float)v1.w;
                tag[8]  += wb[8  * 9 + wo] * (float)v2.x;  tag[9]  += wb[9  * 9 + wo] * (float)v2.y;
                tag[10] += wb[10 * 9 + wo] * (float)v2.z;  tag[11] += wb[11 * 9 + wo] * (float)v2.w;
                tag[12] += wb[12 * 9 + wo] * (float)v3.x;  tag[13] += wb[13 * 9 + wo] * (float)v3.y;
                tag[14] += wb[14 * 9 + wo] * (float)v3.z;  tag[15] += wb[15 * 9 + wo] * (float)v3.w;
                tag[16] += wb[16 * 9 + wo] * (float)v4.x;  tag[17] += wb[17 * 9 + wo] * (float)v4.y;
                tag[18] += wb[18 * 9 + wo] * (float)v4.z;  tag[19] += wb[19 * 9 + wo] * (float)v4.w;
            }
        }
        #pragma unroll
        for (int j = 0; j < 20; ++j) tag[j] *= g_wt_s[br * 20 + j];

        // ---------- IDWT (thread-local 2x2 quad) ----------
        float xt[5][4];
        #pragma unroll
        for (int c = 0; c < 5; ++c) {
            const float LL = tag[c * 4 + 0], LH = tag[c * 4 + 1];
            const float HLv = tag[c * 4 + 2], HHv = tag[c * 4 + 3];
            xt[c][0] = 0.5f * (LL + LH + HLv + HHv);
            xt[c][1] = 0.5f * (LL + LH - HLv - HHv);
            xt[c][2] = 0.5f * (LL - LH + HLv - HHv);
            xt[c][3] = 0.5f * (LL - LH - HLv + HHv);
        }

        // ---------- Phase 4: base 3x3 dwconv via b64 4x6 patches ----------
        float gi[5][4];
        #pragma unroll
        for (int c = 0; c < 5; ++c) {
            float patch[4][6];
            #pragma unroll
            for (int r4 = 0; r4 < 4; ++r4) {
                const float* rp = &s_gln[c][2 * ty + 1 + r4][2 * tx];
                const float2 pa = *(const float2*)(rp);
                const float2 pb = *(const float2*)(rp + 2);
                const float2 pc = *(const float2*)(rp + 4);
                patch[r4][0] = pa.x; patch[r4][1] = pa.y;
                patch[r4][2] = pb.x; patch[r4][3] = pb.y;
                patch[r4][4] = pc.x; patch[r4][5] = pc.y;
            }
            const float* bw = g_base_w + br * 45 + c * 9;
            const float bb2 = g_base_b[br * 5 + c], bs = g_base_s[br * 5 + c];
            #pragma unroll
            for (int p = 0; p < 4; ++p) {
                const int py = p >> 1, px = p & 1;
                float acc = 0.f;
                #pragma unroll
                for (int dy = 0; dy < 3; ++dy)
                    #pragma unroll
                    for (int dx = 0; dx < 3; ++dx)
                        acc += bw[dy * 3 + dx] * patch[py + dy][1 + px + dx];
                gi[c][p] = (acc + bb2) * bs + xt[c][p];
            }
        }

        // ---------- 5x5 pointwise + tail accumulation ----------
        #pragma unroll
        for (int p = 0; p < 4; ++p) {
            #pragma unroll
            for (int o = 0; o < 5; ++o) {
                float v = 0.f;
                #pragma unroll
                for (int c = 0; c < 5; ++c) v += g_pw_w[br * 25 + o * 5 + c] * gi[c][p];
                const int cg = br * 5 + o;
                S1[p] += v;
                S2[p] += v * v;
                const float lw = tail_ln_w[cg];
                #pragma unroll
                for (int o8 = 0; o8 < 8; ++o8)
                    T[p][o8] += tail_w[o8 * 20 + cg] * lw * v;
            }
        }
        __syncthreads();   // before next branch overwrites s_gln / s_unh
    }

    // ---------- Phase 5: tail LN (closed form) + 1x1 + GELU + residual ----------
    float A[8], Bc[8];
    #pragma unroll
    for (int o = 0; o < 8; ++o) {
        float a = 0.f, bb = tail_b[o];
        #pragma unroll
        for (int cg = 0; cg < 20; ++cg) {
            a  += tail_w[o * 20 + cg] * tail_ln_w[cg];
            bb += tail_w[o * 20 + cg] * tail_ln_b[cg];
        }
        A[o] = a; Bc[o] = bb;
    }

    #pragma unroll
    for (int py = 0; py < 2; ++py) {
        const int gy = ty0 + 2 * ty + py;
        const int gx = tx0 + 2 * tx;
        const int rowbase = ((b * CXL) * HL + gy) * HL + gx;

        const int p0 = 2 * py, p1 = 2 * py + 1;
        const float u0    = S1[p0] * 0.05f;
        const float rstd0 = rsqrtf(S2[p0] * 0.05f - u0 * u0 + 1e-6f);
        const float u1    = S1[p1] * 0.05f;
        const float rstd1 = rsqrtf(S2[p1] * 0.05f - u1 * u1 + 1e-6f);

        float2 xl2[8];
        #pragma unroll
        for (int c = 0; c < 8; ++c) xl2[c] = *(const float2*)&xl[rowbase + c * HL * HL];
        const float2 mk = *(const float2*)&mask[(b * HL + gy) * HL + gx];

        #pragma unroll
        for (int o = 0; o < 8; ++o) {
            float rx = res_b[o] + res_w[o * 9 + 8] * mk.x;
            float ry = res_b[o] + res_w[o * 9 + 8] * mk.y;
            #pragma unroll
            for (int c = 0; c < 8; ++c) {
                rx += res_w[o * 9 + c] * xl2[c].x;
                ry += res_w[o * 9 + c] * xl2[c].y;
            }
            float2 ov;
            ov.x = gelu_exact((T[p0][o] - u0 * A[o]) * rstd0 + Bc[o]) + rx;
            ov.y = gelu_exact((T[p1][o] - u1 * A[o]) * rstd1 + Bc[o]) + ry;
            *(float2*)&out[rowbase + o * HL * HL] = ov;
        }
    }
}

extern "C" void kernel_launch(void* const* d_in, const int* in_sizes, int n_in,
                              void* d_out, int out_size, void* d_ws, size_t ws_size,
                              hipStream_t stream) {
    (void)in_sizes; (void)out_size; (void)ws_size;
    if (n_in < 19) return;
    const float* xh        = (const float*)d_in[0];
    const float* xl        = (const float*)d_in[1];
    const float* mask      = (const float*)d_in[2];
    const float* pre_w     = (const float*)d_in[3];
    const float* pre_b     = (const float*)d_in[4];
    const float* g_ln_w    = (const float*)d_in[5];
    const float* g_ln_b    = (const float*)d_in[6];
    const float* g_base_w  = (const float*)d_in[7];
    const float* g_base_b  = (const float*)d_in[8];
    const float* g_base_s  = (const float*)d_in[9];
    const float* g_wt_w    = (const float*)d_in[10];
    const float* g_wt_s    = (const float*)d_in[11];
    const float* g_pw_w    = (const float*)d_in[12];
    const float* tail_ln_w = (const float*)d_in[13];
    const float* tail_ln_b = (const float*)d_in[14];
    const float* tail_w    = (const float*)d_in[15];
    const float* tail_b    = (const float*)d_in[16];
    const float* res_w     = (const float*)d_in[17];
    const float* res_b     = (const float*)d_in[18];
    float* outp = (float*)d_out;
    float* xhp  = (float*)d_ws;        // needs 8*256*256*8*4 = 16.8 MB of scratch

    // Kernel A: pre-projection, channel-interleaved
    pre_project_kernel<<<dim3(BB * HH * HH / 256), dim3(256), 0, stream>>>(
        xh, pre_w, pre_b, xhp);

    // Main fused kernel
    dim3 grid(HL / TS, HL / TS, BB);   // (16, 16, 8) = 2048 blocks
    dim3 block(16, 16, 1);             // 256 threads, each owns a 2x2 output quad
    uem_fused_kernel<<<grid, block, 0, stream>>>(
        xhp, xl, mask, g_ln_w, g_ln_b, g_base_w, g_base_b,
        g_base_s, g_wt_w, g_wt_s, g_pw_w, tail_ln_w, tail_ln_b, tail_w,
        tail_b, res_w, res_b, outp);
}